// Round 1
// baseline (181.781 us; speedup 1.0000x reference)
//
#include <hip/hip_runtime.h>
#include <stdint.h>

#define HH   96
#define WW   96
#define HW   9216
#define CIN  256
#define COUT 256
#define NB   2      // batch
#define NG   4      // groups
#define CG   64     // channels per group
#define KK   9
#define KTOT 2304   // CIN*KK
#define KB   288    // KTOT/8

typedef __attribute__((ext_vector_type(8))) short short8;
typedef __attribute__((ext_vector_type(4))) float f32x4;
typedef __attribute__((ext_vector_type(4))) uint32_t u32x4;

__device__ __forceinline__ uint32_t f2bf(float f) {
    uint32_t u = __builtin_bit_cast(uint32_t, f);
    return (u + 0x7fffu + ((u >> 16) & 1u)) >> 16;   // RNE
}

// ---------------------------------------------------------------------------
// Kernel 1: w_deform (COUT x 2304 fp32) -> bf16, blocked [my][kb][o%128][8]
// ---------------------------------------------------------------------------
__global__ __launch_bounds__(256) void prep_A(const float* __restrict__ wd,
                                              uint16_t* __restrict__ Ablk) {
    int t  = blockIdx.x * 256 + threadIdx.x;   // 73728 = 256*288
    int kb = t % KB;
    int o  = t / KB;
    const float* src = wd + (size_t)o * KTOT + kb * 8;
    float4 a = *(const float4*)src;
    float4 b = *(const float4*)(src + 4);
    int my = o >> 7, ol = o & 127;
    uint16_t* dst = Ablk + (((size_t)my * KB + kb) * 128 + ol) * 8;
    u32x4 v;
    v.x = f2bf(a.x) | (f2bf(a.y) << 16);
    v.y = f2bf(a.z) | (f2bf(a.w) << 16);
    v.z = f2bf(b.x) | (f2bf(b.y) << 16);
    v.w = f2bf(b.z) | (f2bf(b.w) << 16);
    *(u32x4*)dst = v;
}

// ---------------------------------------------------------------------------
// Kernel 2: offsets + bilinear sampling -> S[b][kb][p][8] bf16
// block: 256 thr = 4 waves; all waves share a 64-pixel tile, wave w owns
// channels [w*16, w*16+16) of group g. k = (g*64+c)*9+kk runs contiguously,
// so each lane flushes 16B chunks (coalesced across lanes).
// ---------------------------------------------------------------------------
__global__ __launch_bounds__(256) void sampler(const float* __restrict__ feature,
                                               const float* __restrict__ pred,
                                               const float* __restrict__ woff,
                                               uint16_t* __restrict__ S) {
    __shared__ float wo[NG * KK * 2 * 4];   // 288 floats
    int tid = threadIdx.x;
    for (int i = tid; i < NG * KK * 2 * 4; i += 256) wo[i] = woff[i];
    __syncthreads();

    int lane = tid & 63, wv = tid >> 6;
    int p = blockIdx.x * 64 + lane;
    int g = blockIdx.y;
    int b = blockIdx.z;
    int hy = p / WW, hx = p % WW;

    float4 ps4 = *(const float4*)(pred + ((size_t)b * HW + p) * 4);

    int   idx0[KK], idx1[KK], idx2[KK], idx3[KK];
    float w0[KK], w1[KK], w2[KK], w3[KK];
#pragma unroll
    for (int kk = 0; kk < KK; ++kk) {
        int o = (g * KK + kk) * 2;
        const float* wy = &wo[o * 4];
        float offy = ps4.x * wy[0] + ps4.y * wy[1] + ps4.z * wy[2] + ps4.w * wy[3];
        float offx = ps4.x * wy[4] + ps4.y * wy[5] + ps4.z * wy[6] + ps4.w * wy[7];
        float py = (float)(hy - 1 + kk / 3) + offy;
        float px = (float)(hx - 1 + kk % 3) + offx;
        float fy = floorf(py), fx = floorf(px);
        int y0 = (int)fy, x0 = (int)fx;
        float ly = py - fy, lx = px - fx;
        int y1 = y0 + 1, x1 = x0 + 1;
        bool vy0 = (y0 >= 0) && (y0 < HH), vy1 = (y1 >= 0) && (y1 < HH);
        bool vx0 = (x0 >= 0) && (x0 < WW), vx1 = (x1 >= 0) && (x1 < WW);
        int cy0 = min(max(y0, 0), HH - 1), cy1 = min(max(y1, 0), HH - 1);
        int cx0 = min(max(x0, 0), WW - 1), cx1 = min(max(x1, 0), WW - 1);
        idx0[kk] = cy0 * WW + cx0;  w0[kk] = (vy0 && vx0) ? (1.f - ly) * (1.f - lx) : 0.f;
        idx1[kk] = cy0 * WW + cx1;  w1[kk] = (vy0 && vx1) ? (1.f - ly) * lx        : 0.f;
        idx2[kk] = cy1 * WW + cx0;  w2[kk] = (vy1 && vx0) ? ly * (1.f - lx)        : 0.f;
        idx3[kk] = cy1 * WW + cx1;  w3[kk] = (vy1 && vx1) ? ly * lx                : 0.f;
    }

    int c0 = wv * 16;
    const float* fbase = feature + ((size_t)(b * CIN + g * CG + c0)) * HW;
    int kstart = (g * CG + c0) * KK;               // multiple of 8 (144*(4g+wv))
    uint16_t* Sp = S + (((size_t)b * KB + (kstart >> 3)) * HW + p) * 8;

#pragma unroll
    for (int j = 0; j < 18; ++j) {                 // 18 chunks of 8 k's = 144
        uint32_t pk[4];
#pragma unroll
        for (int e = 0; e < 8; ++e) {
            int kl = j * 8 + e;                    // 0..143 (compile-time)
            int c  = kl / 9, kk = kl % 9;
            const float* fp = fbase + c * HW;
            float v = w0[kk] * fp[idx0[kk]] + w1[kk] * fp[idx1[kk]]
                    + w2[kk] * fp[idx2[kk]] + w3[kk] * fp[idx3[kk]];
            uint32_t bfv = f2bf(v);
            if (e & 1) pk[e >> 1] |= bfv << 16;
            else       pk[e >> 1]  = bfv;
        }
        u32x4 vv = {pk[0], pk[1], pk[2], pk[3]};
        *(u32x4*)Sp = vv;
        Sp += (size_t)HW * 8;                      // next kb row
    }
}

// ---------------------------------------------------------------------------
// Kernel 3: out[b,o,p] = relu( sum_k A[o,k] * S[k,p] )  (bf16 MFMA 16x16x32)
// 128x128 tile, BK=32, 4 waves each 64x64; chunked LDS layout [kc][row][8]
// makes every frag a consecutive-lane ds_read_b128 (conflict-free).
// ---------------------------------------------------------------------------
__global__ __launch_bounds__(256) void gemm_kernel(const uint16_t* __restrict__ S,
                                                   const uint16_t* __restrict__ Ablk,
                                                   float* __restrict__ out) {
    __shared__ uint16_t sA[4 * 128 * 8];   // [kc][o][8]
    __shared__ uint16_t sB[4 * 128 * 8];   // [kc][p][8]

    int tid = threadIdx.x;
    int lane = tid & 63, wv = tid >> 6;
    int wr = wv >> 1, wc = wv & 1;
    int col0 = blockIdx.x * 128;           // p tile (72 tiles)
    int my   = blockIdx.y;                 // o tile (2)
    int b    = blockIdx.z;

    const uint16_t* Ag = Ablk + (size_t)my * KB * 128 * 8;
    const uint16_t* Bg = S    + (size_t)b  * KB * HW  * 8;

    f32x4 acc[4][4];
#pragma unroll
    for (int m = 0; m < 4; ++m)
#pragma unroll
        for (int n = 0; n < 4; ++n) acc[m][n] = (f32x4){0.f, 0.f, 0.f, 0.f};

    int kc = lane >> 4, il = lane & 15;

    for (int k0 = 0; k0 < KTOT; k0 += 32) {
        int kb0 = k0 >> 3;
        // ---- stage: wave wv owns k-chunk row (kb0+wv); 2 halves of 64 lanes
        {
            const uint16_t* ga = Ag + ((size_t)(kb0 + wv) * 128) * 8;
            uint16_t* la = sA + wv * 128 * 8;
            const uint16_t* gb = Bg + ((size_t)(kb0 + wv) * HW + col0) * 8;
            uint16_t* lb = sB + wv * 128 * 8;
#pragma unroll
            for (int h = 0; h < 2; ++h) {
                __builtin_amdgcn_global_load_lds(
                    (const __attribute__((address_space(1))) uint32_t*)(ga + (h * 64 + lane) * 8),
                    (__attribute__((address_space(3))) uint32_t*)(la + h * 64 * 8),
                    16, 0, 0);
                __builtin_amdgcn_global_load_lds(
                    (const __attribute__((address_space(1))) uint32_t*)(gb + (h * 64 + lane) * 8),
                    (__attribute__((address_space(3))) uint32_t*)(lb + h * 64 * 8),
                    16, 0, 0);
            }
        }
        __syncthreads();

        short8 af[4], bf[4];
#pragma unroll
        for (int m = 0; m < 4; ++m)
            af[m] = *(const short8*)(sA + ((kc * 128) + (wr * 64 + m * 16 + il)) * 8);
#pragma unroll
        for (int n = 0; n < 4; ++n)
            bf[n] = *(const short8*)(sB + ((kc * 128) + (wc * 64 + n * 16 + il)) * 8);

#pragma unroll
        for (int m = 0; m < 4; ++m)
#pragma unroll
            for (int n = 0; n < 4; ++n)
                acc[m][n] = __builtin_amdgcn_mfma_f32_16x16x32_bf16(af[m], bf[n], acc[m][n], 0, 0, 0);

        __syncthreads();
    }

    // epilogue: C/D layout col=lane&15, row=(lane>>4)*4+r ; fused ReLU
    int r4 = (lane >> 4) * 4;
    size_t obase = ((size_t)b * COUT + my * 128 + wr * 64) * HW + col0 + wc * 64;
#pragma unroll
    for (int m = 0; m < 4; ++m)
#pragma unroll
        for (int n = 0; n < 4; ++n)
#pragma unroll
            for (int r = 0; r < 4; ++r) {
                float v = acc[m][n][r];
                v = v > 0.f ? v : 0.f;
                out[obase + (size_t)(m * 16 + r4 + r) * HW + n * 16 + il] = v;
            }
}

// ---------------------------------------------------------------------------
extern "C" void kernel_launch(void* const* d_in, const int* in_sizes, int n_in,
                              void* d_out, int out_size, void* d_ws, size_t ws_size,
                              hipStream_t stream) {
    (void)in_sizes; (void)n_in; (void)out_size; (void)ws_size;
    const float* feature = (const float*)d_in[0];
    const float* pred    = (const float*)d_in[1];
    const float* woff    = (const float*)d_in[2];
    const float* wdef    = (const float*)d_in[3];
    float* out = (float*)d_out;

    const size_t S_BYTES = (size_t)NB * KB * HW * 8 * 2;   // 84,934,656
    uint16_t* S    = (uint16_t*)d_ws;
    uint16_t* Ablk = (uint16_t*)((char*)d_ws + S_BYTES);

    hipLaunchKernelGGL(prep_A, dim3(288), dim3(256), 0, stream, wdef, Ablk);
    hipLaunchKernelGGL(sampler, dim3(HW / 64, NG, NB), dim3(256), 0, stream,
                       feature, pred, woff, S);
    hipLaunchKernelGGL(gemm_kernel, dim3(HW / 128, 2, NB), dim3(256), 0, stream,
                       S, Ablk, out);
}

// Round 2
// 100.452 us; speedup vs baseline: 1.8096x; 1.8096x over previous
//
#include <hip/hip_runtime.h>
#include <stdint.h>

#define HH   96
#define WW   96
#define HW   9216
#define CIN  256
#define COUT 256
#define NB   2      // batch
#define NG   4      // groups
#define CG   64     // channels per group
#define KK   9
#define KTOT 2304   // CIN*KK
#define KB   288    // KTOT/8
#define TS   8      // sampler pixel tile side
#define WIN  12     // staged window side (TS + 4)

typedef __attribute__((ext_vector_type(8))) short short8;
typedef __attribute__((ext_vector_type(4))) float f32x4;
typedef __attribute__((ext_vector_type(4))) uint32_t u32x4;

__device__ __forceinline__ uint32_t f2bf(float f) {
    uint32_t u = __builtin_bit_cast(uint32_t, f);
    return (u + 0x7fffu + ((u >> 16) & 1u)) >> 16;   // RNE
}

// ---------------------------------------------------------------------------
// Kernel 1: w_deform (COUT x CIN x 9 fp32) -> bf16, blocked [my][kb][o%128][8]
// K-order is kk-major: k' = kk*256 + c  (must match sampler's S layout)
// ---------------------------------------------------------------------------
__global__ __launch_bounds__(256) void prep_A(const float* __restrict__ wd,
                                              uint16_t* __restrict__ Ablk) {
    int t  = blockIdx.x * 256 + threadIdx.x;   // 73728 = 256*288
    int kb = t % KB;
    int o  = t / KB;
    int kkA = kb >> 5;            // (kb*8)/256
    int c0A = (kb & 31) * 8;      // (kb*8)%256
    const float* src = wd + (size_t)o * KTOT + c0A * KK + kkA;
    float a[8];
#pragma unroll
    for (int e = 0; e < 8; ++e) a[e] = src[e * KK];
    int my = o >> 7, ol = o & 127;
    uint16_t* dst = Ablk + (((size_t)my * KB + kb) * 128 + ol) * 8;
    u32x4 v;
    v.x = f2bf(a[0]) | (f2bf(a[1]) << 16);
    v.y = f2bf(a[2]) | (f2bf(a[3]) << 16);
    v.z = f2bf(a[4]) | (f2bf(a[5]) << 16);
    v.w = f2bf(a[6]) | (f2bf(a[7]) << 16);
    *(u32x4*)dst = v;
}

// ---------------------------------------------------------------------------
// Kernel 2: offsets + bilinear sampling -> S[b][kb][p][8] bf16 (kk-major K)
// block = 8x8 pixel tile x one group (64 ch); feature window staged in LDS.
// Separable pair weights: rows (r,r+1) x cols (q,q+1), clamp-aware, verified
// equivalent to the reference's 4-corner valid-masked bilinear.
// Per-(kk,lane) bounds check with global-memory fallback keeps it correct for
// arbitrary offsets (never taken for this data; exec-masked skip).
// ---------------------------------------------------------------------------
__global__ __launch_bounds__(256) void sampler(const float* __restrict__ feature,
                                               const float* __restrict__ pred,
                                               const float* __restrict__ woff,
                                               uint16_t* __restrict__ S) {
    __shared__ float ft[CG * WIN * WIN];   // 36864 B
    __shared__ float wo[NG * KK * 2 * 4];  // 1152 B

    int tid = threadIdx.x;
    int g = blockIdx.y, b = blockIdx.z;
    int ty = blockIdx.x / (WW / TS), tx = blockIdx.x % (WW / TS);
    int r0 = ty * TS, c0 = tx * TS;
    int rlo = min(max(r0 - 2, 0), HH - WIN);
    int clo = min(max(c0 - 2, 0), WW - WIN);

    for (int i = tid; i < NG * KK * 2 * 4; i += 256) wo[i] = woff[i];

    const float* fg = feature + ((size_t)(b * CIN + g * CG)) * HW;
    for (int e = tid; e < CG * WIN * WIN; e += 256) {
        int ch = e / (WIN * WIN);
        int re = e - ch * (WIN * WIN);
        int rr = re / WIN, cc = re - rr * WIN;
        ft[e] = fg[(size_t)ch * HW + (rlo + rr) * WW + clo + cc];
    }
    __syncthreads();

    int lane = tid & 63, wv = tid >> 6;
    int lr = lane >> 3, lc = lane & 7;
    int hy = r0 + lr, hx = c0 + lc;
    int p = hy * WW + hx;
    float4 ps4 = *(const float4*)(pred + ((size_t)b * HW + p) * 4);

    const float* ftw = ft + (wv * 16) * (WIN * WIN);
    const float* fgw = fg + (size_t)(wv * 16) * HW;     // fallback base

#pragma unroll
    for (int kk = 0; kk < KK; ++kk) {
        const float* wy = &wo[(g * KK + kk) * 8];
        float offy = ps4.x * wy[0] + ps4.y * wy[1] + ps4.z * wy[2] + ps4.w * wy[3];
        float offx = ps4.x * wy[4] + ps4.y * wy[5] + ps4.z * wy[6] + ps4.w * wy[7];
        float py = (float)(hy - 1 + kk / 3) + offy;
        float px = (float)(hx - 1 + kk % 3) + offx;
        float fy = floorf(py), fx = floorf(px);
        int y0 = (int)fy, x0 = (int)fx;
        float ly = py - fy, lx = px - fx;
        int r = min(max(y0, 0), HH - 2);
        int q = min(max(x0, 0), WW - 2);
        float wyA = (y0 == r) ? (1.f - ly) : ((y0 == -1) ? ly : 0.f);
        float wyB = (y0 == r) ? ly : ((y0 == HH - 1) ? (1.f - ly) : 0.f);
        float wxA = (x0 == q) ? (1.f - lx) : ((x0 == -1) ? lx : 0.f);
        float wxB = (x0 == q) ? lx : ((x0 == WW - 1) ? (1.f - lx) : 0.f);

        bool fast = (r >= rlo) & (r <= rlo + WIN - 2) &
                    (q >= clo) & (q <= clo + WIN - 2);

        // output chunk base: k' = kk*256 + g*64 + wv*16 (+ ch8*8)
        uint16_t* Sp = S + (((size_t)b * KB + (kk * 32 + g * 8 + wv * 2)) * HW + p) * 8;

        if (fast) {
            int base = (r - rlo) * WIN + (q - clo);
#pragma unroll
            for (int ch8 = 0; ch8 < 2; ++ch8) {
                uint32_t pk[4];
#pragma unroll
                for (int e = 0; e < 8; ++e) {
                    const float* fp = ftw + (ch8 * 8 + e) * (WIN * WIN) + base;
                    float t0 = fp[0], t1 = fp[1];          // ds_read2_b32
                    float u0 = fp[WIN], u1 = fp[WIN + 1];  // ds_read2_b32
                    float v = wyA * (wxA * t0 + wxB * t1) + wyB * (wxA * u0 + wxB * u1);
                    uint32_t bfv = f2bf(v);
                    if (e & 1) pk[e >> 1] |= bfv << 16;
                    else       pk[e >> 1]  = bfv;
                }
                u32x4 vv = {pk[0], pk[1], pk[2], pk[3]};
                *(u32x4*)(Sp) = vv;
                Sp += (size_t)HW * 8;
            }
        } else {
            size_t gb = (size_t)r * WW + q;
#pragma unroll
            for (int ch8 = 0; ch8 < 2; ++ch8) {
                uint32_t pk[4];
#pragma unroll
                for (int e = 0; e < 8; ++e) {
                    const float* fp = fgw + (size_t)(ch8 * 8 + e) * HW + gb;
                    float t0 = fp[0], t1 = fp[1];
                    float u0 = fp[WW], u1 = fp[WW + 1];
                    float v = wyA * (wxA * t0 + wxB * t1) + wyB * (wxA * u0 + wxB * u1);
                    uint32_t bfv = f2bf(v);
                    if (e & 1) pk[e >> 1] |= bfv << 16;
                    else       pk[e >> 1]  = bfv;
                }
                u32x4 vv = {pk[0], pk[1], pk[2], pk[3]};
                *(u32x4*)(Sp) = vv;
                Sp += (size_t)HW * 8;
            }
        }
    }
}

// ---------------------------------------------------------------------------
// Kernel 3: out[b,o,p] = relu( sum_k A[o,k] * S[k,p] )  (bf16 MFMA 16x16x32)
// 128x128 tile, BK=32, 4 waves each 64x64; chunked LDS layout [kc][row][8]
// makes every frag a consecutive-lane ds_read_b128 (conflict-free).
// ---------------------------------------------------------------------------
__global__ __launch_bounds__(256) void gemm_kernel(const uint16_t* __restrict__ S,
                                                   const uint16_t* __restrict__ Ablk,
                                                   float* __restrict__ out) {
    __shared__ uint16_t sA[4 * 128 * 8];   // [kc][o][8]
    __shared__ uint16_t sB[4 * 128 * 8];   // [kc][p][8]

    int tid = threadIdx.x;
    int lane = tid & 63, wv = tid >> 6;
    int wr = wv >> 1, wc = wv & 1;
    int col0 = blockIdx.x * 128;           // p tile (72)
    int my   = blockIdx.y;                 // o tile (2)
    int b    = blockIdx.z;

    const uint16_t* Ag = Ablk + (size_t)my * KB * 128 * 8;
    const uint16_t* Bg = S    + (size_t)b  * KB * HW  * 8;

    f32x4 acc[4][4];
#pragma unroll
    for (int m = 0; m < 4; ++m)
#pragma unroll
        for (int n = 0; n < 4; ++n) acc[m][n] = (f32x4){0.f, 0.f, 0.f, 0.f};

    int kc = lane >> 4, il = lane & 15;

    for (int k0 = 0; k0 < KTOT; k0 += 32) {
        int kb0 = k0 >> 3;
        {
            const uint16_t* ga = Ag + ((size_t)(kb0 + wv) * 128) * 8;
            uint16_t* la = sA + wv * 128 * 8;
            const uint16_t* gb = Bg + ((size_t)(kb0 + wv) * HW + col0) * 8;
            uint16_t* lb = sB + wv * 128 * 8;
#pragma unroll
            for (int h = 0; h < 2; ++h) {
                __builtin_amdgcn_global_load_lds(
                    (const __attribute__((address_space(1))) uint32_t*)(ga + (h * 64 + lane) * 8),
                    (__attribute__((address_space(3))) uint32_t*)(la + h * 64 * 8),
                    16, 0, 0);
                __builtin_amdgcn_global_load_lds(
                    (const __attribute__((address_space(1))) uint32_t*)(gb + (h * 64 + lane) * 8),
                    (__attribute__((address_space(3))) uint32_t*)(lb + h * 64 * 8),
                    16, 0, 0);
            }
        }
        __syncthreads();

        short8 af[4], bf[4];
#pragma unroll
        for (int m = 0; m < 4; ++m)
            af[m] = *(const short8*)(sA + ((kc * 128) + (wr * 64 + m * 16 + il)) * 8);
#pragma unroll
        for (int n = 0; n < 4; ++n)
            bf[n] = *(const short8*)(sB + ((kc * 128) + (wc * 64 + n * 16 + il)) * 8);

#pragma unroll
        for (int m = 0; m < 4; ++m)
#pragma unroll
            for (int n = 0; n < 4; ++n)
                acc[m][n] = __builtin_amdgcn_mfma_f32_16x16x32_bf16(af[m], bf[n], acc[m][n], 0, 0, 0);

        __syncthreads();
    }

    int r4 = (lane >> 4) * 4;
    size_t obase = ((size_t)b * COUT + my * 128 + wr * 64) * HW + col0 + wc * 64;
#pragma unroll
    for (int m = 0; m < 4; ++m)
#pragma unroll
        for (int n = 0; n < 4; ++n)
#pragma unroll
            for (int r = 0; r < 4; ++r) {
                float v = acc[m][n][r];
                v = v > 0.f ? v : 0.f;
                out[obase + (size_t)(m * 16 + r4 + r) * HW + n * 16 + il] = v;
            }
}

// ---------------------------------------------------------------------------
extern "C" void kernel_launch(void* const* d_in, const int* in_sizes, int n_in,
                              void* d_out, int out_size, void* d_ws, size_t ws_size,
                              hipStream_t stream) {
    (void)in_sizes; (void)n_in; (void)out_size; (void)ws_size;
    const float* feature = (const float*)d_in[0];
    const float* pred    = (const float*)d_in[1];
    const float* woff    = (const float*)d_in[2];
    const float* wdef    = (const float*)d_in[3];
    float* out = (float*)d_out;

    const size_t S_BYTES = (size_t)NB * KB * HW * 8 * 2;   // 84,934,656
    uint16_t* S    = (uint16_t*)d_ws;
    uint16_t* Ablk = (uint16_t*)((char*)d_ws + S_BYTES);

    hipLaunchKernelGGL(prep_A, dim3(288), dim3(256), 0, stream, wdef, Ablk);
    hipLaunchKernelGGL(sampler, dim3((HH / TS) * (WW / TS), NG, NB), dim3(256), 0, stream,
                       feature, pred, woff, S);
    hipLaunchKernelGGL(gemm_kernel, dim3(HW / 128, 2, NB), dim3(256), 0, stream,
                       S, Ablk, out);
}